// Round 11
// baseline (1913.436 us; speedup 1.0000x reference)
//
#include <hip/hip_runtime.h>
#include <cfloat>
#include <math.h>

#define N 96
#define DIN 16
#define HID 256
#define LAT 128
#define EDGE 4656
#define OUTDIM 6192

typedef unsigned long long ull;

// ---- ws float offsets ----
enum {
  WH1   = 0,            // 96*256
  WX1   = 24576,        // 96*256
  WH2   = 49152,        // 96*256
  WGH   = 73728,        // 256
  WKL   = 73984,        // 4
  WOUTP = 73988,        // 4656
  WOUTX = 78644,        // 1536
  WDEGT = 80180,        // 96
  WDEGR = 80276,        // 96
  WDT   = 80372,        // 96
  WDR   = 80468,        // 96
  WB    = 80564,        // 96*96
  WSDT  = 89780,        // 96*96  SdT[a][i]
  WMSK  = 98996,        // 192 ull = 384 floats (8B aligned)
  WXA   = 99380,        // 96*104 row-major padded
  WXB   = 109364,       // 96*104
  WXAT  = 119348,       // 96*96  col-major (xT[a][i] = x[i][a])
  WXBT  = 128564,       // 96*96
  WSSP  = 137780        // 2*96
};

__device__ __forceinline__ int triidx(int i, int j) { // requires i<=j
  return i * N - (i * (i - 1)) / 2 + (j - i);
}

// DPP wave64 reduce steps (pure VALU) — validated R9/R10 (absmax 0)
#define FMAXDPP(m, ctrl, rmask)                                                    \
  { int _d = __builtin_amdgcn_update_dpp(__float_as_int(m), __float_as_int(m),     \
                                         (ctrl), (rmask), 0xF, false);             \
    m = fmaxf(m, __int_as_float(_d)); }
#define IMINDPP(x, ctrl, rmask)                                                    \
  { int _d = __builtin_amdgcn_update_dpp((x), (x), (ctrl), (rmask), 0xF, false);   \
    x = min(x, _d); }

// serial top-2 row scan (first-index tie-break for both slots)
__device__ __forceinline__ void scan_top2(const float* __restrict__ Xrow,
                                          float& m1, int& a1, float& m2, int& a2) {
  m1 = -FLT_MAX; m2 = -FLT_MAX; a1 = 0; a2 = 0;
  for (int c = 0; c < N; ++c) {
    float v = Xrow[c];
    if (v > m1) { m2 = m1; a2 = a1; m1 = v; a1 = c; }
    else if (v > m2) { m2 = v; a2 = c; }
  }
}

// ---- h1 = (adj @ feats) @ conv1_w ; block=row i, 256 thr ----
__global__ void k_enc1(const float* __restrict__ adj, const float* __restrict__ feats,
                       const float* __restrict__ w1, float* __restrict__ h1) {
  int i = blockIdx.x, t = threadIdx.x;
  __shared__ float p[16][17];
  __shared__ float t1[16];
  int k = t & 15, part = t >> 4;
  float s = 0.f;
  for (int j = part * 6; j < part * 6 + 6; ++j) s += adj[i * N + j] * feats[j * DIN + k];
  p[part][k] = s;
  __syncthreads();
  if (t < 16) { float q = 0.f; for (int r = 0; r < 16; ++r) q += p[r][t]; t1[t] = q; }
  __syncthreads();
  float h = 0.f;
  for (int kk = 0; kk < 16; ++kk) h += t1[kk] * w1[kk * HID + t];
  h1[i * HID + t] = h;
}

// ---- BN1 + ReLU ; block=col c, 128 thr ----
__global__ void k_bn1(const float* __restrict__ h1, const float* __restrict__ gg,
                      const float* __restrict__ bb, float* __restrict__ x1) {
  int c = blockIdx.x, t = threadIdx.x;
  float v = (t < N) ? h1[t * HID + c] : 0.f;
  __shared__ float s1[128], s2[128];
  s1[t] = v; s2[t] = v * v; __syncthreads();
  for (int s = 64; s > 0; s >>= 1) { if (t < s) { s1[t] += s1[t + s]; s2[t] += s2[t + s]; } __syncthreads(); }
  float mu = s1[0] / (float)N;
  float var = s2[0] / (float)N - mu * mu;
  float inv = rsqrtf(var + 1e-5f);
  if (t < N) x1[t * HID + c] = fmaxf((v - mu) * inv * gg[c] + bb[c], 0.f);
}

// ---- h2 = (adj @ x1) @ conv2_w ; block=row i, 256 thr ----
__global__ void k_enc2(const float* __restrict__ adj, const float* __restrict__ x1,
                       const float* __restrict__ w2, float* __restrict__ h2) {
  int i = blockIdx.x, t = threadIdx.x;
  __shared__ float t2[HID];
  float s = 0.f;
  for (int j = 0; j < N; ++j) s += adj[i * N + j] * x1[j * HID + t];
  t2[t] = s;
  __syncthreads();
  float h = 0.f;
  for (int k = 0; k < HID; ++k) h += t2[k] * w2[k * HID + t];
  h2[i * HID + t] = h;
}

// ---- BN2 then gh = column sums ; block=col c ----
__global__ void k_bn2gh(const float* __restrict__ h2, const float* __restrict__ gg,
                        const float* __restrict__ bb, float* __restrict__ gh) {
  int c = blockIdx.x, t = threadIdx.x;
  float v = (t < N) ? h2[t * HID + c] : 0.f;
  __shared__ float s1[128], s2[128];
  s1[t] = v; s2[t] = v * v; __syncthreads();
  for (int s = 64; s > 0; s >>= 1) { if (t < s) { s1[t] += s1[t + s]; s2[t] += s2[t + s]; } __syncthreads(); }
  float mu = s1[0] / (float)N;
  float var = s2[0] / (float)N - mu * mu;
  float inv = rsqrtf(var + 1e-5f);
  __syncthreads();
  float xv = (t < N) ? ((v - mu) * inv * gg[c] + bb[c]) : 0.f;
  s1[t] = xv; __syncthreads();
  for (int s = 64; s > 0; s >>= 1) { if (t < s) s1[t] += s1[t + s]; __syncthreads(); }
  if (t == 0) gh[c] = s1[0];
}

// ---- VAE (redundant per block) + decoder ; 25 blocks x 256 thr ----
__global__ void k_vaedec(const float* __restrict__ gh,
                         const float* __restrict__ e11w, const float* __restrict__ e11b,
                         const float* __restrict__ e12w, const float* __restrict__ e12b,
                         const float* __restrict__ d1w, const float* __restrict__ d1b,
                         const float* __restrict__ d2w, const float* __restrict__ d2b,
                         const float* __restrict__ eps, float* __restrict__ kl,
                         float* __restrict__ outp, float* __restrict__ outx) {
  int t = threadIdx.x;
  __shared__ float ghs[HID], zs[LAT], h1d[LAT], kr[LAT];
  ghs[t] = gh[t];
  __syncthreads();
  if (t < LAT) {
    float a = e11b[t], c = e12b[t];
    for (int k = 0; k < HID; ++k) {
      float g = ghs[k];
      a = fmaf(e11w[t * HID + k], g, a);
      c = fmaf(e12w[t * HID + k], g, c);
    }
    zs[t] = eps[t] * expf(0.5f * c) + a;
    kr[t] = 1.f + c - a * a - expf(c);
  }
  __syncthreads();
  if (blockIdx.x == 0 && t == 0) {
    float s = 0.f;
    for (int k = 0; k < LAT; ++k) s += kr[k];
    kl[0] = -0.5f * s / (float)(N * N);
  }
  if (t < LAT) {
    float hv = d1b[t];
    for (int k = 0; k < LAT; ++k) hv = fmaf(d1w[t * LAT + k], zs[k], hv);
    h1d[t] = fmaxf(hv, 0.f);
  }
  __syncthreads();
  int o = blockIdx.x * 256 + t;
  if (o < OUTDIM) {
    const float4* wr = (const float4*)(d2w + o * LAT);
    float s = d2b[o];
    for (int k4 = 0; k4 < 32; ++k4) {
      float4 v = wr[k4];
      s = fmaf(v.x, h1d[k4 * 4], fmaf(v.y, h1d[k4 * 4 + 1],
            fmaf(v.z, h1d[k4 * 4 + 2], fmaf(v.w, h1d[k4 * 4 + 3], s))));
    }
    if (o < EDGE) outp[o] = 1.f / (1.f + expf(-s));
    else outx[o - EDGE] = s;
  }
}

// ---- degrees, diagonals, adjacency bitmasks ; block=row a, 128 thr ----
__global__ void k_recon(const float* __restrict__ adj, const float* __restrict__ outp,
                        float* __restrict__ degt, float* __restrict__ degr,
                        float* __restrict__ dt, float* __restrict__ dr,
                        ull* __restrict__ mskg) {
  int a = blockIdx.x, t = threadIdx.x;
  float rv = 0.f, av = 0.f;
  if (t < N) {
    int i2 = min(a, t), j2 = max(a, t);
    rv = outp[triidx(i2, j2)];
    av = adj[a * N + t];
    if (t == a) { dr[a] = rv; dt[a] = av; }
  }
  ull bal = __ballot(t < N && av > 0.5f);
  if ((t & 63) == 0) mskg[a * 2 + (t >> 6)] = bal;
  __shared__ float s1[128], s2[128];
  s1[t] = rv; s2[t] = av; __syncthreads();
  for (int s = 64; s > 0; s >>= 1) { if (t < s) { s1[t] += s1[t + s]; s2[t] += s2[t + s]; } __syncthreads(); }
  if (t == 0) { degr[a] = s1[0]; degt[a] = s2[0]; }
}

// ---- B rows, SdT rows, x0 (both layouts) ; block=row a, 128 thr ----
__global__ void k_simab(const float* __restrict__ outp,
                        const float* __restrict__ degt, const float* __restrict__ degr,
                        const float* __restrict__ dt, const float* __restrict__ dr,
                        float* __restrict__ Bg, float* __restrict__ SdTg,
                        float* __restrict__ x0, float* __restrict__ x0T) {
  int a = blockIdx.x, t = threadIdx.x;
  if (t < N) {
    int i2 = min(a, t), j2 = max(a, t);
    float rv = outp[triidx(i2, j2)];
    Bg[a * N + t] = (t == a) ? 0.f : rv * dr[a] * dr[t];
    SdTg[a * N + t] = dt[t] * dr[a] / (fabsf(degt[t] - degr[a]) + 1.f);
    x0[t * 104 + a] = 1.f / (float)N;
    x0T[a * N + t] = 1.f / (float)N;
  }
}

// ---- one MPM iteration ; block = column a, 256 thr (2 threads per row) ----
__global__ __launch_bounds__(256) void k_mpm(
    const float* __restrict__ xin,  const float* __restrict__ xinT,
    float* __restrict__ xout, float* __restrict__ xoutT,
    const float* __restrict__ Bg, const float* __restrict__ SdTg,
    const ull* __restrict__ mskg,
    const float* __restrict__ sspP, float* __restrict__ sspC, int first) {
  const int a = blockIdx.x, t = threadIdx.x;
  const int w = t >> 6, l = t & 63;
  const int j = t >> 1, h = t & 1;          // row j, half h (b in [48h,48h+48))
  __shared__ __align__(16) float Bs[96];
  __shared__ float Sd[96], Xold[96], Ms[96], Xnew[96];
  __shared__ float red[4], red2[4];
  const bool act = (j < N);
  if (t < N) {
    Bs[t] = Bg[a * N + t];
    Sd[t] = SdTg[a * N + t];
    Xold[t] = xinT[a * N + t];
  }
  float sv = (!first && t < N) ? sspP[t] : 0.f;
#pragma unroll
  for (int off = 32; off >= 1; off >>= 1) sv += __shfl_xor(sv, off);
  if (l == 0) red[w] = sv;
  ull wm = 0;
  if (act) {
    wm = mskg[j * 2 + h];
    if (h == 0) { if (j < 64) wm &= ~(1ull << j); }
    else        { if (j >= 64) wm &= ~(1ull << (j - 64)); }
  }
  __syncthreads();
  const float inv = first ? 1.f : rsqrtf(red[0] + red[1] + red[2] + red[3]);
  if (act) {
    const float4* xr = (const float4*)(xin + j * 104) + h * 12;
    const float4* Bs4 = (const float4*)Bs + h * 12;
    float m0 = 0.f;
#pragma unroll
    for (int k = 0; k < 12; ++k) {
      float4 xq = xr[k];
      float4 bq = Bs4[k];
      m0 = fmaxf(m0, fmaxf(fmaxf(bq.x * xq.x, bq.y * xq.y),
                           fmaxf(bq.z * xq.z, bq.w * xq.w)));
    }
    m0 = fmaxf(m0, __shfl_xor(m0, 1));
    if (h == 0) Ms[j] = m0;
  }
  __syncthreads();
  float ss = 0.f;
  if (act) {
    float macc = 0.f;
    ull mm = wm;
    int base = h * 64;
    while (mm) { int jj = __builtin_ctzll(mm); mm &= mm - 1; macc += Ms[base + jj]; }
    macc += __shfl_xor(macc, 1);
    if (h == 0) {
      float v = fmaf(Xold[j], Sd[j], macc) * inv;
      Xnew[j] = v;
      xout[j * 104 + a] = v;
      ss = v * v;
    }
  }
#pragma unroll
  for (int off = 32; off >= 1; off >>= 1) ss += __shfl_xor(ss, off);
  if (l == 0) red2[w] = ss;
  __syncthreads();
  if (t == 0) sspC[a] = red2[0] + red2[1] + red2[2] + red2[3];
  if (t < 24) {
    float4 q = *(const float4*)&Xnew[4 * t];
    *(float4*)&xoutT[a * N + 4 * t] = q;
  }
}

// ---- greedy (single wave, top-2 tracking, DPP reduce, no barriers) + losses ----
__global__ __launch_bounds__(128) void k_fin(
    const float* __restrict__ xfin,      // [96][104] row-major
    const ull* __restrict__ mskg,
    const float* __restrict__ feats,
    const float* __restrict__ outp, const float* __restrict__ outx,
    const float* __restrict__ kl, float* __restrict__ out) {
  int t = threadIdx.x;
  int w = t >> 6, l = t & 63;
  __shared__ float X[96 * 100];
  __shared__ float RM1[96], RM2[96];
  __shared__ int RA1[96], RA2[96];
  __shared__ int INDS[96];
  __shared__ ull MSKl[192];
  __shared__ float rf[2], rb[2];
  for (int e = t; e < 96 * 26; e += 128) {     // 96 rows x 26 quad slots (24 used)
    int i = e / 26, q = e - i * 26;
    if (q < 24) {
      float4 v = *(const float4*)&xfin[i * 104 + 4 * q];
      *(float4*)&X[i * 100 + 4 * q] = v;
    }
  }
  if (t < 96) { MSKl[2 * t] = mskg[2 * t]; MSKl[2 * t + 1] = mskg[2 * t + 1]; }
  __syncthreads();

  // initial top-2 per row (96 threads in parallel)
  if (t < N) {
    float m1, m2; int a1, a2;
    scan_top2(&X[t * 100], m1, a1, m2, a2);
    RM1[t] = m1; RA1[t] = a1; RM2[t] = m2; RA2[t] = a2;
  }
  __syncthreads();

  // single-wave greedy: lane l owns row l (A) and row 64+l (B, l<32)
  if (w == 0) {
    float m1A = RM1[l], m2A = RM2[l];
    int a1A = RA1[l], a2A = RA2[l];
    bool alA = true, v2A = (m2A != -FLT_MAX);
    float m1B = -FLT_MAX, m2B = -FLT_MAX; int a1B = 0, a2B = 0;
    bool alB = (l < 32), v2B = false;
    if (l < 32) {
      m1B = RM1[64 + l]; m2B = RM2[64 + l];
      a1B = RA1[64 + l]; a2B = RA2[64 + l];
      v2B = (m2B != -FLT_MAX);
    }
    for (int step = 0; step < N; ++step) {
      float vc = alA ? m1A : -FLT_MAX;
      if (alB) vc = fmaxf(vc, m1B);
      FMAXDPP(vc, 0x111, 0xF);
      FMAXDPP(vc, 0x112, 0xF);
      FMAXDPP(vc, 0x114, 0xF);
      FMAXDPP(vc, 0x118, 0xF);
      FMAXDPP(vc, 0x142, 0xA);
      FMAXDPP(vc, 0x143, 0xC);
      float Mw = __int_as_float(__builtin_amdgcn_readlane(__float_as_int(vc), 63));
      int idx = 0x7FFFFFFF;
      if (alB && m1B == Mw) idx = (64 + l) * N + a1B;
      if (alA && m1A == Mw) idx = l * N + a1A;   // A preferred: smaller flat
      IMINDPP(idx, 0x111, 0xF);
      IMINDPP(idx, 0x112, 0xF);
      IMINDPP(idx, 0x114, 0xF);
      IMINDPP(idx, 0x118, 0xF);
      IMINDPP(idx, 0x142, 0xA);
      IMINDPP(idx, 0x143, 0xC);
      int F = __builtin_amdgcn_readlane(idx, 63);
      int r = F / N, c = F - (F / N) * N;
      if (l == 0) INDS[c] = r;
      if (l == r) alA = false;
      if (alB && (64 + l) == r) alB = false;
      X[l * 100 + c] = -FLT_MAX;                 // own-row clears (same-lane use only)
      if (l < 32) X[(64 + l) * 100 + c] = -FLT_MAX;
      if (alA) {
        if (a1A == c) {
          if (v2A) { m1A = m2A; a1A = a2A; v2A = false; }
          else { scan_top2(&X[l * 100], m1A, a1A, m2A, a2A); v2A = (m2A != -FLT_MAX); }
        } else if (v2A && a2A == c) v2A = false;
      }
      if (alB) {
        if (a1B == c) {
          if (v2B) { m1B = m2B; a1B = a2B; v2B = false; }
          else { scan_top2(&X[(64 + l) * 100], m1B, a1B, m2B, a2B); v2B = (m2B != -FLT_MAX); }
        } else if (v2B && a2B == c) v2B = false;
      }
    }
  }
  __syncthreads();

  // ---- losses ----
  float accf = 0.f;
  for (int p = t; p < N * DIN; p += 128) {
    int i = p >> 4, k = p & 15;
    float d = outx[p] - feats[INDS[i] * DIN + k];
    accf += d * d;
  }
  float accb = 0.f;
  for (int e = t; e < EDGE; e += 128) {
    int i = (int)((193.0f - sqrtf(193.0f * 193.0f - 8.0f * (float)e)) * 0.5f);
    if (i < 0) i = 0; if (i > 95) i = 95;
    while (i < 95 && triidx(i + 1, i + 1) <= e) ++i;
    while (i > 0 && triidx(i, i) > e) --i;
    int j = i + (e - triidx(i, i));
    int ri = INDS[i], rj = INDS[j];
    float tv = (float)((MSKl[ri * 2 + (rj >> 6)] >> (rj & 63)) & 1ull);
    float pr = outp[e];
    float l1 = fmaxf(logf(pr), -100.f);
    float l0 = fmaxf(log1pf(-pr), -100.f);
    accb += tv * l1 + (1.f - tv) * l0;
  }
#pragma unroll
  for (int off = 32; off >= 1; off >>= 1) { accf += __shfl_xor(accf, off); accb += __shfl_xor(accb, off); }
  if (l == 0) { rf[w] = accf; rb[w] = accb; }
  __syncthreads();
  if (t == 0) {
    float ff = rf[0] + rf[1];
    float bb = rb[0] + rb[1];
    out[0] = (-bb / (float)EDGE) + kl[0] + ff / (float)(N * DIN);
  }
}

extern "C" void kernel_launch(void* const* d_in, const int* in_sizes, int n_in,
                              void* d_out, int out_size, void* d_ws, size_t ws_size,
                              hipStream_t stream) {
  const float* feats = (const float*)d_in[0];
  const float* adj   = (const float*)d_in[1];
  const float* w1    = (const float*)d_in[2];
  const float* w2    = (const float*)d_in[3];
  const float* bn1g  = (const float*)d_in[4];
  const float* bn1b  = (const float*)d_in[5];
  const float* bn2g  = (const float*)d_in[6];
  const float* bn2b  = (const float*)d_in[7];
  const float* e11w  = (const float*)d_in[8];
  const float* e11b  = (const float*)d_in[9];
  const float* e12w  = (const float*)d_in[10];
  const float* e12b  = (const float*)d_in[11];
  const float* d1w   = (const float*)d_in[12];
  const float* d1b   = (const float*)d_in[13];
  const float* d2w   = (const float*)d_in[14];
  const float* d2b   = (const float*)d_in[15];
  const float* eps   = (const float*)d_in[16];

  float* ws   = (float*)d_ws;
  float* h1   = ws + WH1;
  float* x1   = ws + WX1;
  float* h2   = ws + WH2;
  float* gh   = ws + WGH;
  float* kl   = ws + WKL;
  float* outp = ws + WOUTP;
  float* outx = ws + WOUTX;
  float* degt = ws + WDEGT;
  float* degr = ws + WDEGR;
  float* dt   = ws + WDT;
  float* dr   = ws + WDR;
  float* Bg   = ws + WB;
  float* SdTg = ws + WSDT;
  ull*   mskg = (ull*)(ws + WMSK);
  float* xa   = ws + WXA;
  float* xb   = ws + WXB;
  float* xaT  = ws + WXAT;
  float* xbT  = ws + WXBT;
  float* ssp  = ws + WSSP;
  float* out  = (float*)d_out;

  k_enc1<<<96, 256, 0, stream>>>(adj, feats, w1, h1);
  k_bn1<<<256, 128, 0, stream>>>(h1, bn1g, bn1b, x1);
  k_enc2<<<96, 256, 0, stream>>>(adj, x1, w2, h2);
  k_bn2gh<<<256, 128, 0, stream>>>(h2, bn2g, bn2b, gh);
  k_vaedec<<<25, 256, 0, stream>>>(gh, e11w, e11b, e12w, e12b, d1w, d1b,
                                   d2w, d2b, eps, kl, outp, outx);
  k_recon<<<96, 128, 0, stream>>>(adj, outp, degt, degr, dt, dr, mskg);
  k_simab<<<96, 128, 0, stream>>>(outp, degt, degr, dt, dr, Bg, SdTg, xa, xaT);

  for (int m = 0; m < 50; ++m) {
    const float* xi  = (m & 1) ? xb : xa;
    const float* xiT = (m & 1) ? xbT : xaT;
    float* xo        = (m & 1) ? xa : xb;
    float* xoT       = (m & 1) ? xaT : xbT;
    float* sc        = ssp + (m & 1) * N;
    const float* sp  = ssp + ((m & 1) ^ 1) * N;
    k_mpm<<<96, 256, 0, stream>>>(xi, xiT, xo, xoT, Bg, SdTg, mskg, sp, sc,
                                  (m == 0) ? 1 : 0);
  }
  // m=49 odd -> final x in xa
  k_fin<<<1, 128, 0, stream>>>(xa, mskg, feats, outp, outx, kl, out);
}

// Round 12
// 465.787 us; speedup vs baseline: 4.1080x; 4.1080x over previous
//
#include <hip/hip_runtime.h>
#include <cfloat>
#include <math.h>

#define N 96
#define DIN 16
#define HID 256
#define LAT 128
#define EDGE 4656
#define OUTDIM 6192

typedef unsigned long long ull;

// ---- ws float offsets ----
enum {
  WH1   = 0,            // 96*256
  WX1   = 24576,        // 96*256
  WH2   = 49152,        // 96*256
  WGH   = 73728,        // 256
  WKL   = 73984,        // 4
  WOUTP = 73988,        // 4656
  WOUTX = 78644,        // 1536
  WDEGT = 80180,        // 96
  WDEGR = 80276,        // 96
  WDT   = 80372,        // 96
  WDR   = 80468,        // 96
  WB    = 80564,        // 96*96
  WSDT  = 89780,        // 96*96  SdT[a][i]
  WMSK  = 98996,        // 192 ull = 384 floats (8B aligned)
  WXA   = 99380,        // 96*104 row-major padded
  WXB   = 109364,       // 96*104
  WXAT  = 119348,       // 96*96  col-major (xT[a][i] = x[i][a])
  WXBT  = 128564,       // 96*96
  WSSP  = 137780        // 2*96
};

__device__ __forceinline__ int triidx(int i, int j) { // requires i<=j
  return i * N - (i * (i - 1)) / 2 + (j - i);
}

// DPP wave64 reduce steps (pure VALU) — validated R9/R10 (absmax 0)
#define FMAXDPP(m, ctrl, rmask)                                                    \
  { int _d = __builtin_amdgcn_update_dpp(__float_as_int(m), __float_as_int(m),     \
                                         (ctrl), (rmask), 0xF, false);             \
    m = fmaxf(m, __int_as_float(_d)); }

// 4-chain row scan: first-flat-index tie-break (validated R10)
__device__ __forceinline__ void scan_row(const float* __restrict__ Xrow,
                                         float& mOut, int& aOut) {
  const float4* xr4 = (const float4*)Xrow;
  float m0 = -FLT_MAX, m1 = -FLT_MAX, m2 = -FLT_MAX, m3 = -FLT_MAX;
  int a0 = 0, a1 = 1, a2 = 2, a3 = 3;
#pragma unroll
  for (int q = 0; q < 24; ++q) {
    float4 v = xr4[q];
    if (v.x > m0) { m0 = v.x; a0 = 4 * q; }
    if (v.y > m1) { m1 = v.y; a1 = 4 * q + 1; }
    if (v.z > m2) { m2 = v.z; a2 = 4 * q + 2; }
    if (v.w > m3) { m3 = v.w; a3 = 4 * q + 3; }
  }
  if (m1 > m0 || (m1 == m0 && a1 < a0)) { m0 = m1; a0 = a1; }
  if (m3 > m2 || (m3 == m2 && a3 < a2)) { m2 = m3; a2 = a3; }
  if (m2 > m0 || (m2 == m0 && a2 < a0)) { m0 = m2; a0 = a2; }
  mOut = m0; aOut = a0;
}

// ---- h1 = (adj @ feats) @ conv1_w ; block=row i, 256 thr ----
__global__ void k_enc1(const float* __restrict__ adj, const float* __restrict__ feats,
                       const float* __restrict__ w1, float* __restrict__ h1) {
  int i = blockIdx.x, t = threadIdx.x;
  __shared__ float p[16][17];
  __shared__ float t1[16];
  int k = t & 15, part = t >> 4;
  float s = 0.f;
  for (int j = part * 6; j < part * 6 + 6; ++j) s += adj[i * N + j] * feats[j * DIN + k];
  p[part][k] = s;
  __syncthreads();
  if (t < 16) { float q = 0.f; for (int r = 0; r < 16; ++r) q += p[r][t]; t1[t] = q; }
  __syncthreads();
  float h = 0.f;
  for (int kk = 0; kk < 16; ++kk) h += t1[kk] * w1[kk * HID + t];
  h1[i * HID + t] = h;
}

// ---- BN1 + ReLU ; block=col c, 128 thr ----
__global__ void k_bn1(const float* __restrict__ h1, const float* __restrict__ gg,
                      const float* __restrict__ bb, float* __restrict__ x1) {
  int c = blockIdx.x, t = threadIdx.x;
  float v = (t < N) ? h1[t * HID + c] : 0.f;
  __shared__ float s1[128], s2[128];
  s1[t] = v; s2[t] = v * v; __syncthreads();
  for (int s = 64; s > 0; s >>= 1) { if (t < s) { s1[t] += s1[t + s]; s2[t] += s2[t + s]; } __syncthreads(); }
  float mu = s1[0] / (float)N;
  float var = s2[0] / (float)N - mu * mu;
  float inv = rsqrtf(var + 1e-5f);
  if (t < N) x1[t * HID + c] = fmaxf((v - mu) * inv * gg[c] + bb[c], 0.f);
}

// ---- h2 = (adj @ x1) @ conv2_w ; block=row i, 256 thr ----
__global__ void k_enc2(const float* __restrict__ adj, const float* __restrict__ x1,
                       const float* __restrict__ w2, float* __restrict__ h2) {
  int i = blockIdx.x, t = threadIdx.x;
  __shared__ float t2[HID];
  float s = 0.f;
  for (int j = 0; j < N; ++j) s += adj[i * N + j] * x1[j * HID + t];
  t2[t] = s;
  __syncthreads();
  float h = 0.f;
  for (int k = 0; k < HID; ++k) h += t2[k] * w2[k * HID + t];
  h2[i * HID + t] = h;
}

// ---- BN2 then gh = column sums ; block=col c ----
__global__ void k_bn2gh(const float* __restrict__ h2, const float* __restrict__ gg,
                        const float* __restrict__ bb, float* __restrict__ gh) {
  int c = blockIdx.x, t = threadIdx.x;
  float v = (t < N) ? h2[t * HID + c] : 0.f;
  __shared__ float s1[128], s2[128];
  s1[t] = v; s2[t] = v * v; __syncthreads();
  for (int s = 64; s > 0; s >>= 1) { if (t < s) { s1[t] += s1[t + s]; s2[t] += s2[t + s]; } __syncthreads(); }
  float mu = s1[0] / (float)N;
  float var = s2[0] / (float)N - mu * mu;
  float inv = rsqrtf(var + 1e-5f);
  __syncthreads();
  float xv = (t < N) ? ((v - mu) * inv * gg[c] + bb[c]) : 0.f;
  s1[t] = xv; __syncthreads();
  for (int s = 64; s > 0; s >>= 1) { if (t < s) s1[t] += s1[t + s]; __syncthreads(); }
  if (t == 0) gh[c] = s1[0];
}

// ---- VAE (redundant per block) + decoder ; 25 blocks x 256 thr ----
__global__ void k_vaedec(const float* __restrict__ gh,
                         const float* __restrict__ e11w, const float* __restrict__ e11b,
                         const float* __restrict__ e12w, const float* __restrict__ e12b,
                         const float* __restrict__ d1w, const float* __restrict__ d1b,
                         const float* __restrict__ d2w, const float* __restrict__ d2b,
                         const float* __restrict__ eps, float* __restrict__ kl,
                         float* __restrict__ outp, float* __restrict__ outx) {
  int t = threadIdx.x;
  __shared__ float ghs[HID], zs[LAT], h1d[LAT], kr[LAT];
  ghs[t] = gh[t];
  __syncthreads();
  if (t < LAT) {
    float a = e11b[t], c = e12b[t];
    for (int k = 0; k < HID; ++k) {
      float g = ghs[k];
      a = fmaf(e11w[t * HID + k], g, a);
      c = fmaf(e12w[t * HID + k], g, c);
    }
    zs[t] = eps[t] * expf(0.5f * c) + a;
    kr[t] = 1.f + c - a * a - expf(c);
  }
  __syncthreads();
  if (blockIdx.x == 0 && t == 0) {
    float s = 0.f;
    for (int k = 0; k < LAT; ++k) s += kr[k];
    kl[0] = -0.5f * s / (float)(N * N);
  }
  if (t < LAT) {
    float hv = d1b[t];
    for (int k = 0; k < LAT; ++k) hv = fmaf(d1w[t * LAT + k], zs[k], hv);
    h1d[t] = fmaxf(hv, 0.f);
  }
  __syncthreads();
  int o = blockIdx.x * 256 + t;
  if (o < OUTDIM) {
    const float4* wr = (const float4*)(d2w + o * LAT);
    float s = d2b[o];
    for (int k4 = 0; k4 < 32; ++k4) {
      float4 v = wr[k4];
      s = fmaf(v.x, h1d[k4 * 4], fmaf(v.y, h1d[k4 * 4 + 1],
            fmaf(v.z, h1d[k4 * 4 + 2], fmaf(v.w, h1d[k4 * 4 + 3], s))));
    }
    if (o < EDGE) outp[o] = 1.f / (1.f + expf(-s));
    else outx[o - EDGE] = s;
  }
}

// ---- degrees, diagonals, adjacency bitmasks ; block=row a, 128 thr ----
__global__ void k_recon(const float* __restrict__ adj, const float* __restrict__ outp,
                        float* __restrict__ degt, float* __restrict__ degr,
                        float* __restrict__ dt, float* __restrict__ dr,
                        ull* __restrict__ mskg) {
  int a = blockIdx.x, t = threadIdx.x;
  float rv = 0.f, av = 0.f;
  if (t < N) {
    int i2 = min(a, t), j2 = max(a, t);
    rv = outp[triidx(i2, j2)];
    av = adj[a * N + t];
    if (t == a) { dr[a] = rv; dt[a] = av; }
  }
  ull bal = __ballot(t < N && av > 0.5f);
  if ((t & 63) == 0) mskg[a * 2 + (t >> 6)] = bal;
  __shared__ float s1[128], s2[128];
  s1[t] = rv; s2[t] = av; __syncthreads();
  for (int s = 64; s > 0; s >>= 1) { if (t < s) { s1[t] += s1[t + s]; s2[t] += s2[t + s]; } __syncthreads(); }
  if (t == 0) { degr[a] = s1[0]; degt[a] = s2[0]; }
}

// ---- B rows, SdT rows, x0 (both layouts) ; block=row a, 128 thr ----
__global__ void k_simab(const float* __restrict__ outp,
                        const float* __restrict__ degt, const float* __restrict__ degr,
                        const float* __restrict__ dt, const float* __restrict__ dr,
                        float* __restrict__ Bg, float* __restrict__ SdTg,
                        float* __restrict__ x0, float* __restrict__ x0T) {
  int a = blockIdx.x, t = threadIdx.x;
  if (t < N) {
    int i2 = min(a, t), j2 = max(a, t);
    float rv = outp[triidx(i2, j2)];
    Bg[a * N + t] = (t == a) ? 0.f : rv * dr[a] * dr[t];
    SdTg[a * N + t] = dt[t] * dr[a] / (fabsf(degt[t] - degr[a]) + 1.f);
    x0[t * 104 + a] = 1.f / (float)N;
    x0T[a * N + t] = 1.f / (float)N;
  }
}

// ---- one MPM iteration ; block = column a, 256 thr (2 threads per row) ----
__global__ __launch_bounds__(256) void k_mpm(
    const float* __restrict__ xin,  const float* __restrict__ xinT,
    float* __restrict__ xout, float* __restrict__ xoutT,
    const float* __restrict__ Bg, const float* __restrict__ SdTg,
    const ull* __restrict__ mskg,
    const float* __restrict__ sspP, float* __restrict__ sspC, int first) {
  const int a = blockIdx.x, t = threadIdx.x;
  const int w = t >> 6, l = t & 63;
  const int j = t >> 1, h = t & 1;          // row j, half h (b in [48h,48h+48))
  __shared__ __align__(16) float Bs[96];
  __shared__ float Sd[96], Xold[96], Ms[96], Xnew[96];
  __shared__ float red[4], red2[4];
  const bool act = (j < N);
  if (t < N) {
    Bs[t] = Bg[a * N + t];
    Sd[t] = SdTg[a * N + t];
    Xold[t] = xinT[a * N + t];
  }
  float sv = (!first && t < N) ? sspP[t] : 0.f;
#pragma unroll
  for (int off = 32; off >= 1; off >>= 1) sv += __shfl_xor(sv, off);
  if (l == 0) red[w] = sv;
  ull wm = 0;
  if (act) {
    wm = mskg[j * 2 + h];
    if (h == 0) { if (j < 64) wm &= ~(1ull << j); }
    else        { if (j >= 64) wm &= ~(1ull << (j - 64)); }
  }
  __syncthreads();
  const float inv = first ? 1.f : rsqrtf(red[0] + red[1] + red[2] + red[3]);
  if (act) {
    const float4* xr = (const float4*)(xin + j * 104) + h * 12;
    const float4* Bs4 = (const float4*)Bs + h * 12;
    float m0 = 0.f;
#pragma unroll
    for (int k = 0; k < 12; ++k) {
      float4 xq = xr[k];
      float4 bq = Bs4[k];
      m0 = fmaxf(m0, fmaxf(fmaxf(bq.x * xq.x, bq.y * xq.y),
                           fmaxf(bq.z * xq.z, bq.w * xq.w)));
    }
    m0 = fmaxf(m0, __shfl_xor(m0, 1));
    if (h == 0) Ms[j] = m0;
  }
  __syncthreads();
  float ss = 0.f;
  if (act) {
    float macc = 0.f;
    ull mm = wm;
    int base = h * 64;
    while (mm) { int jj = __builtin_ctzll(mm); mm &= mm - 1; macc += Ms[base + jj]; }
    macc += __shfl_xor(macc, 1);
    if (h == 0) {
      float v = fmaf(Xold[j], Sd[j], macc) * inv;
      Xnew[j] = v;
      xout[j * 104 + a] = v;
      ss = v * v;
    }
  }
#pragma unroll
  for (int off = 32; off >= 1; off >>= 1) ss += __shfl_xor(ss, off);
  if (l == 0) red2[w] = ss;
  __syncthreads();
  if (t == 0) sspC[a] = red2[0] + red2[1] + red2[2] + red2[3];
  if (t < 24) {
    float4 q = *(const float4*)&Xnew[4 * t];
    *(float4*)&xoutT[a * N + 4 * t] = q;
  }
}

// ---- greedy (row-per-thread, top-4 reg candidates, DPP+ballot, 1 barrier/step) ----
__global__ __launch_bounds__(128) void k_fin(
    const float* __restrict__ xfin,      // [96][104] row-major
    const ull* __restrict__ mskg,
    const float* __restrict__ feats,
    const float* __restrict__ outp, const float* __restrict__ outx,
    const float* __restrict__ kl, float* __restrict__ out) {
  int t = threadIdx.x;
  int w = t >> 6, l = t & 63;
  __shared__ float X[96 * 100];
  __shared__ int INDS[96];
  __shared__ ull MSKl[192];
  __shared__ float kwM[2][2];
  __shared__ int kwI[2][2];
  __shared__ float rf[2], rb[2];
  for (int e = t; e < 96 * 26; e += 128) {     // 96 rows x 26 quad slots (24 used)
    int i = e / 26, q = e - i * 26;
    if (q < 24) {
      float4 v = *(const float4*)&xfin[i * 104 + 4 * q];
      *(float4*)&X[i * 100 + 4 * q] = v;
    }
  }
  if (t < 96) { MSKl[2 * t] = mskg[2 * t]; MSKl[2 * t + 1] = mskg[2 * t + 1]; }
  __syncthreads();

  // ---- init: top-4 candidates per row (serial insertion, first-index exact) ----
  bool alive = (t < N);
  float bv = -FLT_MAX; int bc = 0;                        // current best
  float v2 = -FLT_MAX, v3 = -FLT_MAX, v4 = -FLT_MAX;      // backups
  int c2 = 0, c3 = 0, c4 = 0;
  bool q2 = false, q3 = false, q4 = false;
  ull ca0 = ~0ull, ca1 = 0xFFFFFFFFull;                   // columns alive
  if (alive) {
    const float* xr = &X[t * 100];
    for (int c = 0; c < N; ++c) {
      float v = xr[c];
      if (v > bv)      { v4 = v3; c4 = c3; v3 = v2; c3 = c2; v2 = bv; c2 = bc; bv = v; bc = c; }
      else if (v > v2) { v4 = v3; c4 = c3; v3 = v2; c3 = c2; v2 = v; c2 = c; }
      else if (v > v3) { v4 = v3; c4 = c3; v3 = v; c3 = c; }
      else if (v > v4) { v4 = v; c4 = c; }
    }
    q2 = (v2 != -FLT_MAX); q3 = (v3 != -FLT_MAX); q4 = (v4 != -FLT_MAX);
  }

  for (int step = 0; step < N; ++step) {
    // per-wave value max (pure VALU DPP)
    float vc = alive ? bv : -FLT_MAX;
    FMAXDPP(vc, 0x111, 0xF);   // row_shr:1
    FMAXDPP(vc, 0x112, 0xF);   // row_shr:2
    FMAXDPP(vc, 0x114, 0xF);   // row_shr:4
    FMAXDPP(vc, 0x118, 0xF);   // row_shr:8
    FMAXDPP(vc, 0x142, 0xA);   // row_bcast15
    FMAXDPP(vc, 0x143, 0xC);   // row_bcast31
    float Mw = __int_as_float(__builtin_amdgcn_readlane(__float_as_int(vc), 63));
    // winner lane = lowest lane with bv==Mw (rows ascend with lane -> smallest flat)
    ull b = __ballot(alive && bv == Mw);
    int wl = (b == 0) ? 0 : (int)__builtin_ctzll(b);
    int sl = step & 1;
    if (l == wl) kwI[sl][w] = (b == 0) ? 0x7FFFFFFF : (t * N + bc);
    if (l == 0) kwM[sl][w] = Mw;
    __syncthreads();
    float M0 = kwM[sl][0], M1 = kwM[sl][1];
    int F = (M1 > M0) ? kwI[sl][1] : kwI[sl][0];   // tie -> wave0 (smaller flats)
    int r = F / N, c = F - (F / N) * N;
    if (t == r) { INDS[c] = r; alive = false; }
    if (t < N) X[t * 100 + c] = -FLT_MAX;          // own-row clear (for rescans)
    if (c < 64) ca0 &= ~(1ull << c); else ca1 &= ~(1ull << (c - 64));
    if (alive && bc == c) {                        // promote next alive candidate
      bool got = false;
      if (q2) { q2 = false; bool al = (c2 < 64) ? ((ca0 >> c2) & 1ull) : ((ca1 >> (c2 - 64)) & 1ull);
                if (al) { bv = v2; bc = c2; got = true; } }
      if (!got && q3) { q3 = false; bool al = (c3 < 64) ? ((ca0 >> c3) & 1ull) : ((ca1 >> (c3 - 64)) & 1ull);
                        if (al) { bv = v3; bc = c3; got = true; } }
      if (!got && q4) { q4 = false; bool al = (c4 < 64) ? ((ca0 >> c4) & 1ull) : ((ca1 >> (c4 - 64)) & 1ull);
                        if (al) { bv = v4; bc = c4; got = true; } }
      if (!got) scan_row(&X[t * 100], bv, bc);     // rare: vectorized rescan
    }
  }
  __syncthreads();

  // ---- losses ----
  float accf = 0.f;
  for (int p = t; p < N * DIN; p += 128) {
    int i = p >> 4, k = p & 15;
    float d = outx[p] - feats[INDS[i] * DIN + k];
    accf += d * d;
  }
  float accb = 0.f;
  for (int e = t; e < EDGE; e += 128) {
    int i = (int)((193.0f - sqrtf(193.0f * 193.0f - 8.0f * (float)e)) * 0.5f);
    if (i < 0) i = 0; if (i > 95) i = 95;
    while (i < 95 && triidx(i + 1, i + 1) <= e) ++i;
    while (i > 0 && triidx(i, i) > e) --i;
    int j = i + (e - triidx(i, i));
    int ri = INDS[i], rj = INDS[j];
    float tv = (float)((MSKl[ri * 2 + (rj >> 6)] >> (rj & 63)) & 1ull);
    float pr = outp[e];
    float l1 = fmaxf(logf(pr), -100.f);
    float l0 = fmaxf(log1pf(-pr), -100.f);
    accb += tv * l1 + (1.f - tv) * l0;
  }
#pragma unroll
  for (int off = 32; off >= 1; off >>= 1) { accf += __shfl_xor(accf, off); accb += __shfl_xor(accb, off); }
  if (l == 0) { rf[w] = accf; rb[w] = accb; }
  __syncthreads();
  if (t == 0) {
    float ff = rf[0] + rf[1];
    float bb = rb[0] + rb[1];
    out[0] = (-bb / (float)EDGE) + kl[0] + ff / (float)(N * DIN);
  }
}

extern "C" void kernel_launch(void* const* d_in, const int* in_sizes, int n_in,
                              void* d_out, int out_size, void* d_ws, size_t ws_size,
                              hipStream_t stream) {
  const float* feats = (const float*)d_in[0];
  const float* adj   = (const float*)d_in[1];
  const float* w1    = (const float*)d_in[2];
  const float* w2    = (const float*)d_in[3];
  const float* bn1g  = (const float*)d_in[4];
  const float* bn1b  = (const float*)d_in[5];
  const float* bn2g  = (const float*)d_in[6];
  const float* bn2b  = (const float*)d_in[7];
  const float* e11w  = (const float*)d_in[8];
  const float* e11b  = (const float*)d_in[9];
  const float* e12w  = (const float*)d_in[10];
  const float* e12b  = (const float*)d_in[11];
  const float* d1w   = (const float*)d_in[12];
  const float* d1b   = (const float*)d_in[13];
  const float* d2w   = (const float*)d_in[14];
  const float* d2b   = (const float*)d_in[15];
  const float* eps   = (const float*)d_in[16];

  float* ws   = (float*)d_ws;
  float* h1   = ws + WH1;
  float* x1   = ws + WX1;
  float* h2   = ws + WH2;
  float* gh   = ws + WGH;
  float* kl   = ws + WKL;
  float* outp = ws + WOUTP;
  float* outx = ws + WOUTX;
  float* degt = ws + WDEGT;
  float* degr = ws + WDEGR;
  float* dt   = ws + WDT;
  float* dr   = ws + WDR;
  float* Bg   = ws + WB;
  float* SdTg = ws + WSDT;
  ull*   mskg = (ull*)(ws + WMSK);
  float* xa   = ws + WXA;
  float* xb   = ws + WXB;
  float* xaT  = ws + WXAT;
  float* xbT  = ws + WXBT;
  float* ssp  = ws + WSSP;
  float* out  = (float*)d_out;

  k_enc1<<<96, 256, 0, stream>>>(adj, feats, w1, h1);
  k_bn1<<<256, 128, 0, stream>>>(h1, bn1g, bn1b, x1);
  k_enc2<<<96, 256, 0, stream>>>(adj, x1, w2, h2);
  k_bn2gh<<<256, 128, 0, stream>>>(h2, bn2g, bn2b, gh);
  k_vaedec<<<25, 256, 0, stream>>>(gh, e11w, e11b, e12w, e12b, d1w, d1b,
                                   d2w, d2b, eps, kl, outp, outx);
  k_recon<<<96, 128, 0, stream>>>(adj, outp, degt, degr, dt, dr, mskg);
  k_simab<<<96, 128, 0, stream>>>(outp, degt, degr, dt, dr, Bg, SdTg, xa, xaT);

  for (int m = 0; m < 50; ++m) {
    const float* xi  = (m & 1) ? xb : xa;
    const float* xiT = (m & 1) ? xbT : xaT;
    float* xo        = (m & 1) ? xa : xb;
    float* xoT       = (m & 1) ? xaT : xbT;
    float* sc        = ssp + (m & 1) * N;
    const float* sp  = ssp + ((m & 1) ^ 1) * N;
    k_mpm<<<96, 256, 0, stream>>>(xi, xiT, xo, xoT, Bg, SdTg, mskg, sp, sc,
                                  (m == 0) ? 1 : 0);
  }
  // m=49 odd -> final x in xa
  k_fin<<<1, 128, 0, stream>>>(xa, mskg, feats, outp, outx, kl, out);
}

// Round 13
// 463.107 us; speedup vs baseline: 4.1317x; 1.0058x over previous
//
#include <hip/hip_runtime.h>
#include <cfloat>
#include <math.h>

#define N 96
#define DIN 16
#define HID 256
#define LAT 128
#define EDGE 4656
#define OUTDIM 6192

typedef unsigned long long ull;

// ---- ws float offsets ----
enum {
  WH1   = 0,            // 96*256
  WX1   = 24576,        // 96*256
  WH2   = 49152,        // 96*256
  WGH   = 73728,        // 256
  WKL   = 73984,        // 4
  WOUTP = 73988,        // 4656
  WOUTX = 78644,        // 1536
  WDEGT = 80180,        // 96
  WDEGR = 80276,        // 96
  WDT   = 80372,        // 96
  WDR   = 80468,        // 96
  WMSK  = 98996,        // 192 ull = 384 floats (8B aligned)
  WXA   = 99380,        // 96*104 row-major padded
  WXB   = 109364,       // 96*104
  WXAT  = 119348,       // 96*96  col-major (xT[a][i] = x[i][a])
  WXBT  = 128564,       // 96*96
  WSSP  = 137780        // 2*96
};

__device__ __forceinline__ int triidx(int i, int j) { // requires i<=j
  return i * N - (i * (i - 1)) / 2 + (j - i);
}

// DPP wave64 reduce steps (pure VALU) — validated R9/R10 (absmax 0)
#define FMAXDPP(m, ctrl, rmask)                                                    \
  { int _d = __builtin_amdgcn_update_dpp(__float_as_int(m), __float_as_int(m),     \
                                         (ctrl), (rmask), 0xF, false);             \
    m = fmaxf(m, __int_as_float(_d)); }
#define IMINDPP(x, ctrl, rmask)                                                    \
  { int _d = __builtin_amdgcn_update_dpp((x), (x), (ctrl), (rmask), 0xF, false);   \
    x = min(x, _d); }

// 4-chain row scan: first-flat-index tie-break (validated R10)
__device__ __forceinline__ void scan_row(const float* __restrict__ Xrow,
                                         float& mOut, int& aOut) {
  const float4* xr4 = (const float4*)Xrow;
  float m0 = -FLT_MAX, m1 = -FLT_MAX, m2 = -FLT_MAX, m3 = -FLT_MAX;
  int a0 = 0, a1 = 1, a2 = 2, a3 = 3;
#pragma unroll
  for (int q = 0; q < 24; ++q) {
    float4 v = xr4[q];
    if (v.x > m0) { m0 = v.x; a0 = 4 * q; }
    if (v.y > m1) { m1 = v.y; a1 = 4 * q + 1; }
    if (v.z > m2) { m2 = v.z; a2 = 4 * q + 2; }
    if (v.w > m3) { m3 = v.w; a3 = 4 * q + 3; }
  }
  if (m1 > m0 || (m1 == m0 && a1 < a0)) { m0 = m1; a0 = a1; }
  if (m3 > m2 || (m3 == m2 && a3 < a2)) { m2 = m3; a2 = a3; }
  if (m2 > m0 || (m2 == m0 && a2 < a0)) { m0 = m2; a0 = a2; }
  mOut = m0; aOut = a0;
}

// ---- h1 = (adj @ feats) @ conv1_w ; block=row i, 256 thr ----
__global__ void k_enc1(const float* __restrict__ adj, const float* __restrict__ feats,
                       const float* __restrict__ w1, float* __restrict__ h1) {
  int i = blockIdx.x, t = threadIdx.x;
  __shared__ float p[16][17];
  __shared__ float t1[16];
  int k = t & 15, part = t >> 4;
  float s = 0.f;
  for (int j = part * 6; j < part * 6 + 6; ++j) s += adj[i * N + j] * feats[j * DIN + k];
  p[part][k] = s;
  __syncthreads();
  if (t < 16) { float q = 0.f; for (int r = 0; r < 16; ++r) q += p[r][t]; t1[t] = q; }
  __syncthreads();
  float h = 0.f;
  for (int kk = 0; kk < 16; ++kk) h += t1[kk] * w1[kk * HID + t];
  h1[i * HID + t] = h;
}

// ---- BN1 + ReLU ; block=col c, 128 thr ----
__global__ void k_bn1(const float* __restrict__ h1, const float* __restrict__ gg,
                      const float* __restrict__ bb, float* __restrict__ x1) {
  int c = blockIdx.x, t = threadIdx.x;
  float v = (t < N) ? h1[t * HID + c] : 0.f;
  __shared__ float s1[128], s2[128];
  s1[t] = v; s2[t] = v * v; __syncthreads();
  for (int s = 64; s > 0; s >>= 1) { if (t < s) { s1[t] += s1[t + s]; s2[t] += s2[t + s]; } __syncthreads(); }
  float mu = s1[0] / (float)N;
  float var = s2[0] / (float)N - mu * mu;
  float inv = rsqrtf(var + 1e-5f);
  if (t < N) x1[t * HID + c] = fmaxf((v - mu) * inv * gg[c] + bb[c], 0.f);
}

// ---- h2 = (adj @ x1) @ conv2_w ; block=row i, 256 thr ----
__global__ void k_enc2(const float* __restrict__ adj, const float* __restrict__ x1,
                       const float* __restrict__ w2, float* __restrict__ h2) {
  int i = blockIdx.x, t = threadIdx.x;
  __shared__ float t2[HID];
  float s = 0.f;
  for (int j = 0; j < N; ++j) s += adj[i * N + j] * x1[j * HID + t];
  t2[t] = s;
  __syncthreads();
  float h = 0.f;
  for (int k = 0; k < HID; ++k) h += t2[k] * w2[k * HID + t];
  h2[i * HID + t] = h;
}

// ---- BN2 then gh = column sums ; block=col c ----
__global__ void k_bn2gh(const float* __restrict__ h2, const float* __restrict__ gg,
                        const float* __restrict__ bb, float* __restrict__ gh) {
  int c = blockIdx.x, t = threadIdx.x;
  float v = (t < N) ? h2[t * HID + c] : 0.f;
  __shared__ float s1[128], s2[128];
  s1[t] = v; s2[t] = v * v; __syncthreads();
  for (int s = 64; s > 0; s >>= 1) { if (t < s) { s1[t] += s1[t + s]; s2[t] += s2[t + s]; } __syncthreads(); }
  float mu = s1[0] / (float)N;
  float var = s2[0] / (float)N - mu * mu;
  float inv = rsqrtf(var + 1e-5f);
  __syncthreads();
  float xv = (t < N) ? ((v - mu) * inv * gg[c] + bb[c]) : 0.f;
  s1[t] = xv; __syncthreads();
  for (int s = 64; s > 0; s >>= 1) { if (t < s) s1[t] += s1[t + s]; __syncthreads(); }
  if (t == 0) gh[c] = s1[0];
}

// ---- VAE (redundant per block) + decoder ; 25 blocks x 256 thr ----
__global__ void k_vaedec(const float* __restrict__ gh,
                         const float* __restrict__ e11w, const float* __restrict__ e11b,
                         const float* __restrict__ e12w, const float* __restrict__ e12b,
                         const float* __restrict__ d1w, const float* __restrict__ d1b,
                         const float* __restrict__ d2w, const float* __restrict__ d2b,
                         const float* __restrict__ eps, float* __restrict__ kl,
                         float* __restrict__ outp, float* __restrict__ outx) {
  int t = threadIdx.x;
  __shared__ float ghs[HID], zs[LAT], h1d[LAT], kr[LAT];
  ghs[t] = gh[t];
  __syncthreads();
  if (t < LAT) {
    float a = e11b[t], c = e12b[t];
    for (int k = 0; k < HID; ++k) {
      float g = ghs[k];
      a = fmaf(e11w[t * HID + k], g, a);
      c = fmaf(e12w[t * HID + k], g, c);
    }
    zs[t] = eps[t] * expf(0.5f * c) + a;
    kr[t] = 1.f + c - a * a - expf(c);
  }
  __syncthreads();
  if (blockIdx.x == 0 && t == 0) {
    float s = 0.f;
    for (int k = 0; k < LAT; ++k) s += kr[k];
    kl[0] = -0.5f * s / (float)(N * N);
  }
  if (t < LAT) {
    float hv = d1b[t];
    for (int k = 0; k < LAT; ++k) hv = fmaf(d1w[t * LAT + k], zs[k], hv);
    h1d[t] = fmaxf(hv, 0.f);
  }
  __syncthreads();
  int o = blockIdx.x * 256 + t;
  if (o < OUTDIM) {
    const float4* wr = (const float4*)(d2w + o * LAT);
    float s = d2b[o];
    for (int k4 = 0; k4 < 32; ++k4) {
      float4 v = wr[k4];
      s = fmaf(v.x, h1d[k4 * 4], fmaf(v.y, h1d[k4 * 4 + 1],
            fmaf(v.z, h1d[k4 * 4 + 2], fmaf(v.w, h1d[k4 * 4 + 3], s))));
    }
    if (o < EDGE) outp[o] = 1.f / (1.f + expf(-s));
    else outx[o - EDGE] = s;
  }
}

// ---- degrees, diagonals, bitmasks, x0 init ; block=row a, 128 thr ----
__global__ void k_prep(const float* __restrict__ adj, const float* __restrict__ outp,
                       float* __restrict__ degt, float* __restrict__ degr,
                       float* __restrict__ dt, float* __restrict__ dr,
                       ull* __restrict__ mskg, float* __restrict__ x0,
                       float* __restrict__ x0T) {
  int a = blockIdx.x, t = threadIdx.x;
  float rv = 0.f, av = 0.f;
  if (t < N) {
    int i2 = min(a, t), j2 = max(a, t);
    rv = outp[triidx(i2, j2)];
    av = adj[a * N + t];
    if (t == a) { dr[a] = rv; dt[a] = av; }
  }
  ull bal = __ballot(t < N && av > 0.5f);
  if ((t & 63) == 0) mskg[a * 2 + (t >> 6)] = bal;
  // x0 init: block a owns row a of both layouts
  if (t < 104) x0[a * 104 + t] = 1.f / (float)N;
  if (t < N) x0T[a * N + t] = 1.f / (float)N;
  __shared__ float s1[128], s2[128];
  s1[t] = rv; s2[t] = av; __syncthreads();
  for (int s = 64; s > 0; s >>= 1) { if (t < s) { s1[t] += s1[t + s]; s2[t] += s2[t + s]; } __syncthreads(); }
  if (t == 0) { degr[a] = s1[0]; degt[a] = s2[0]; }
}

// ---- one MPM iteration ; block = column a, 256 thr (2 threads per row) ----
// Bs built on the fly from outp; Sd computed in-register; no Xold/Xnew staging.
__global__ __launch_bounds__(256) void k_mpm(
    const float* __restrict__ xin,  const float* __restrict__ xinT,
    float* __restrict__ xout, float* __restrict__ xoutT,
    const float* __restrict__ outp,
    const float* __restrict__ degt, const float* __restrict__ degr,
    const float* __restrict__ dt, const float* __restrict__ dr,
    const ull* __restrict__ mskg,
    const float* __restrict__ sspP, float* __restrict__ sspC, int first) {
  const int a = blockIdx.x, t = threadIdx.x;
  const int w = t >> 6, l = t & 63;
  const int j = t >> 1, h = t & 1;          // row j, half h (b in [48h,48h+48))
  __shared__ __align__(16) float Bs[96];
  __shared__ float Ms[96];
  __shared__ float red[4], red2[4];
  const bool act = (j < N);
  const float drA = dr[a];
  const float dgrA = degr[a];
  if (t < N) {
    int i2 = min(a, t), j2 = max(a, t);
    float rv = outp[triidx(i2, j2)];
    Bs[t] = (t == a) ? 0.f : rv * drA * dr[t];
  }
  float sv = (!first && t < N) ? sspP[t] : 0.f;
#pragma unroll
  for (int off = 32; off >= 1; off >>= 1) sv += __shfl_xor(sv, off);
  if (l == 0) red[w] = sv;
  ull wm = 0;
  if (act) {
    wm = mskg[j * 2 + h];
    if (h == 0) { if (j < 64) wm &= ~(1ull << j); }
    else        { if (j >= 64) wm &= ~(1ull << (j - 64)); }
  }
  __syncthreads();
  const float inv = first ? 1.f : rsqrtf(red[0] + red[1] + red[2] + red[3]);
  // max phase: pair (j,0),(j,1) splits b-range; combine with 1 intra-wave shfl
  if (act) {
    const float4* xr = (const float4*)(xin + j * 104) + h * 12;
    const float4* Bs4 = (const float4*)Bs + h * 12;
    float m0 = 0.f;
#pragma unroll
    for (int k = 0; k < 12; ++k) {
      float4 xq = xr[k];
      float4 bq = Bs4[k];
      m0 = fmaxf(m0, fmaxf(fmaxf(bq.x * xq.x, bq.y * xq.y),
                           fmaxf(bq.z * xq.z, bq.w * xq.w)));
    }
    m0 = fmaxf(m0, __shfl_xor(m0, 1));
    if (h == 0) Ms[j] = m0;
  }
  __syncthreads();
  // sum phase: halves take their mask word, combine with 1 shfl
  float ss = 0.f;
  if (act) {
    float macc = 0.f;
    ull mm = wm;
    int base = h * 64;
    while (mm) { int jj = __builtin_ctzll(mm); mm &= mm - 1; macc += Ms[base + jj]; }
    macc += __shfl_xor(macc, 1);
    if (h == 0) {
      float sd = dt[j] * drA / (fabsf(degt[j] - dgrA) + 1.f);
      float v = fmaf(xinT[a * N + j], sd, macc) * inv;
      xout[j * 104 + a] = v;
      xoutT[a * N + j] = v;
      ss = v * v;
    }
  }
#pragma unroll
  for (int off = 32; off >= 1; off >>= 1) ss += __shfl_xor(ss, off);
  if (l == 0) red2[w] = ss;
  __syncthreads();
  if (t == 0) sspC[a] = red2[0] + red2[1] + red2[2] + red2[3];
}

// ---- greedy (row-per-thread + DPP per-wave reduce, 1 barrier/step) + losses ----
// VERBATIM R10 structure (benched 166 us, absmax 0)
__global__ __launch_bounds__(128) void k_fin(
    const float* __restrict__ xfin,      // [96][104] row-major
    const ull* __restrict__ mskg,
    const float* __restrict__ feats,
    const float* __restrict__ outp, const float* __restrict__ outx,
    const float* __restrict__ kl, float* __restrict__ out) {
  int t = threadIdx.x;
  int w = t >> 6, l = t & 63;
  __shared__ float X[96 * 100];
  __shared__ int INDS[96];
  __shared__ ull MSKl[192];
  __shared__ float kwM[2][2];
  __shared__ int kwI[2][2];
  __shared__ float rf[2], rb[2];
  for (int e = t; e < 96 * 26; e += 128) {     // 96 rows x 26 quad slots (24 used)
    int i = e / 26, q = e - i * 26;
    if (q < 24) {
      float4 v = *(const float4*)&xfin[i * 104 + 4 * q];
      *(float4*)&X[i * 100 + 4 * q] = v;
    }
  }
  if (t < 96) { MSKl[2 * t] = mskg[2 * t]; MSKl[2 * t + 1] = mskg[2 * t + 1]; }
  __syncthreads();

  // row-per-thread incremental state
  bool alive = (t < N);
  float mT = -FLT_MAX; int aT = 0;
  if (alive) scan_row(&X[t * 100], mT, aT);

  for (int step = 0; step < N; ++step) {
    // per-wave value max (pure VALU DPP)
    float vc = alive ? mT : -FLT_MAX;
    FMAXDPP(vc, 0x111, 0xF);   // row_shr:1
    FMAXDPP(vc, 0x112, 0xF);   // row_shr:2
    FMAXDPP(vc, 0x114, 0xF);   // row_shr:4
    FMAXDPP(vc, 0x118, 0xF);   // row_shr:8
    FMAXDPP(vc, 0x142, 0xA);   // row_bcast15
    FMAXDPP(vc, 0x143, 0xC);   // row_bcast31
    float Mw = __int_as_float(__builtin_amdgcn_readlane(__float_as_int(vc), 63));
    // per-wave first flat index among value==Mw
    int idx = (alive && mT == Mw) ? (t * N + aT) : 0x7FFFFFFF;
    IMINDPP(idx, 0x111, 0xF);
    IMINDPP(idx, 0x112, 0xF);
    IMINDPP(idx, 0x114, 0xF);
    IMINDPP(idx, 0x118, 0xF);
    IMINDPP(idx, 0x142, 0xA);
    IMINDPP(idx, 0x143, 0xC);
    int Iw = __builtin_amdgcn_readlane(idx, 63);
    // cross-wave combine via double-buffered slot: ONE barrier per step
    int sl = step & 1;
    if (l == 0) { kwM[sl][w] = Mw; kwI[sl][w] = Iw; }
    __syncthreads();
    float M0 = kwM[sl][0], M1 = kwM[sl][1];
    int F = (M1 > M0) ? kwI[sl][1] : kwI[sl][0];   // tie -> wave0 (smaller flats)
    int r = F / N, c = F - (F / N) * N;
    if (t == r) { INDS[c] = r; alive = false; }
    if (t < N) X[t * 100 + c] = -FLT_MAX;          // own-row clear (no hazard)
    if (alive && aT == c) scan_row(&X[t * 100], mT, aT);  // parallel rescan
  }
  __syncthreads();

  // ---- losses ----
  float accf = 0.f;
  for (int p = t; p < N * DIN; p += 128) {
    int i = p >> 4, k = p & 15;
    float d = outx[p] - feats[INDS[i] * DIN + k];
    accf += d * d;
  }
  float accb = 0.f;
  for (int e = t; e < EDGE; e += 128) {
    int i = (int)((193.0f - sqrtf(193.0f * 193.0f - 8.0f * (float)e)) * 0.5f);
    if (i < 0) i = 0; if (i > 95) i = 95;
    while (i < 95 && triidx(i + 1, i + 1) <= e) ++i;
    while (i > 0 && triidx(i, i) > e) --i;
    int j = i + (e - triidx(i, i));
    int ri = INDS[i], rj = INDS[j];
    float tv = (float)((MSKl[ri * 2 + (rj >> 6)] >> (rj & 63)) & 1ull);
    float pr = outp[e];
    float l1 = fmaxf(logf(pr), -100.f);
    float l0 = fmaxf(log1pf(-pr), -100.f);
    accb += tv * l1 + (1.f - tv) * l0;
  }
#pragma unroll
  for (int off = 32; off >= 1; off >>= 1) { accf += __shfl_xor(accf, off); accb += __shfl_xor(accb, off); }
  if (l == 0) { rf[w] = accf; rb[w] = accb; }
  __syncthreads();
  if (t == 0) {
    float ff = rf[0] + rf[1];
    float bb = rb[0] + rb[1];
    out[0] = (-bb / (float)EDGE) + kl[0] + ff / (float)(N * DIN);
  }
}

extern "C" void kernel_launch(void* const* d_in, const int* in_sizes, int n_in,
                              void* d_out, int out_size, void* d_ws, size_t ws_size,
                              hipStream_t stream) {
  const float* feats = (const float*)d_in[0];
  const float* adj   = (const float*)d_in[1];
  const float* w1    = (const float*)d_in[2];
  const float* w2    = (const float*)d_in[3];
  const float* bn1g  = (const float*)d_in[4];
  const float* bn1b  = (const float*)d_in[5];
  const float* bn2g  = (const float*)d_in[6];
  const float* bn2b  = (const float*)d_in[7];
  const float* e11w  = (const float*)d_in[8];
  const float* e11b  = (const float*)d_in[9];
  const float* e12w  = (const float*)d_in[10];
  const float* e12b  = (const float*)d_in[11];
  const float* d1w   = (const float*)d_in[12];
  const float* d1b   = (const float*)d_in[13];
  const float* d2w   = (const float*)d_in[14];
  const float* d2b   = (const float*)d_in[15];
  const float* eps   = (const float*)d_in[16];

  float* ws   = (float*)d_ws;
  float* h1   = ws + WH1;
  float* x1   = ws + WX1;
  float* h2   = ws + WH2;
  float* gh   = ws + WGH;
  float* kl   = ws + WKL;
  float* outp = ws + WOUTP;
  float* outx = ws + WOUTX;
  float* degt = ws + WDEGT;
  float* degr = ws + WDEGR;
  float* dt   = ws + WDT;
  float* dr   = ws + WDR;
  ull*   mskg = (ull*)(ws + WMSK);
  float* xa   = ws + WXA;
  float* xb   = ws + WXB;
  float* xaT  = ws + WXAT;
  float* xbT  = ws + WXBT;
  float* ssp  = ws + WSSP;
  float* out  = (float*)d_out;

  k_enc1<<<96, 256, 0, stream>>>(adj, feats, w1, h1);
  k_bn1<<<256, 128, 0, stream>>>(h1, bn1g, bn1b, x1);
  k_enc2<<<96, 256, 0, stream>>>(adj, x1, w2, h2);
  k_bn2gh<<<256, 128, 0, stream>>>(h2, bn2g, bn2b, gh);
  k_vaedec<<<25, 256, 0, stream>>>(gh, e11w, e11b, e12w, e12b, d1w, d1b,
                                   d2w, d2b, eps, kl, outp, outx);
  k_prep<<<96, 128, 0, stream>>>(adj, outp, degt, degr, dt, dr, mskg, xa, xaT);

  for (int m = 0; m < 50; ++m) {
    const float* xi  = (m & 1) ? xb : xa;
    const float* xiT = (m & 1) ? xbT : xaT;
    float* xo        = (m & 1) ? xa : xb;
    float* xoT       = (m & 1) ? xaT : xbT;
    float* sc        = ssp + (m & 1) * N;
    const float* sp  = ssp + ((m & 1) ^ 1) * N;
    k_mpm<<<96, 256, 0, stream>>>(xi, xiT, xo, xoT, outp, degt, degr, dt, dr,
                                  mskg, sp, sc, (m == 0) ? 1 : 0);
  }
  // m=49 odd -> final x in xa
  k_fin<<<1, 128, 0, stream>>>(xa, mskg, feats, outp, outx, kl, out);
}

// Round 14
// 452.034 us; speedup vs baseline: 4.2329x; 1.0245x over previous
//
#include <hip/hip_runtime.h>
#include <cfloat>
#include <math.h>

#define N 96
#define DIN 16
#define HID 256
#define LAT 128
#define EDGE 4656
#define OUTDIM 6192

typedef unsigned long long ull;

// ---- ws float offsets ----
enum {
  WH1   = 0,            // 96*256
  WX1   = 24576,        // 96*256
  WH2   = 49152,        // 96*256
  WGH   = 73728,        // 256
  WKL   = 73984,        // 4
  WOUTP = 73988,        // 4656
  WOUTX = 78644,        // 1536
  WDEGT = 80180,        // 96
  WDEGR = 80276,        // 96
  WDT   = 80372,        // 96
  WDR   = 80468,        // 96
  WMSK  = 98996,        // 192 ull = 384 floats (8B aligned)
  WXA   = 99380,        // 96*104 row-major padded
  WXB   = 109364,       // 96*104
  WXAT  = 119348,       // 96*96  col-major (xT[a][i] = x[i][a])
  WXBT  = 128564,       // 96*96
  WSSP  = 137780        // 2*96
};

__device__ __forceinline__ int triidx(int i, int j) { // requires i<=j
  return i * N - (i * (i - 1)) / 2 + (j - i);
}

// DPP wave64 reduce steps (pure VALU) — validated R9/R10 (absmax 0)
#define FMAXDPP(m, ctrl, rmask)                                                    \
  { int _d = __builtin_amdgcn_update_dpp(__float_as_int(m), __float_as_int(m),     \
                                         (ctrl), (rmask), 0xF, false);             \
    m = fmaxf(m, __int_as_float(_d)); }

// 4-chain row scan: first-flat-index tie-break (validated R10)
__device__ __forceinline__ void scan_row(const float* __restrict__ Xrow,
                                         float& mOut, int& aOut) {
  const float4* xr4 = (const float4*)Xrow;
  float m0 = -FLT_MAX, m1 = -FLT_MAX, m2 = -FLT_MAX, m3 = -FLT_MAX;
  int a0 = 0, a1 = 1, a2 = 2, a3 = 3;
#pragma unroll
  for (int q = 0; q < 24; ++q) {
    float4 v = xr4[q];
    if (v.x > m0) { m0 = v.x; a0 = 4 * q; }
    if (v.y > m1) { m1 = v.y; a1 = 4 * q + 1; }
    if (v.z > m2) { m2 = v.z; a2 = 4 * q + 2; }
    if (v.w > m3) { m3 = v.w; a3 = 4 * q + 3; }
  }
  if (m1 > m0 || (m1 == m0 && a1 < a0)) { m0 = m1; a0 = a1; }
  if (m3 > m2 || (m3 == m2 && a3 < a2)) { m2 = m3; a2 = a3; }
  if (m2 > m0 || (m2 == m0 && a2 < a0)) { m0 = m2; a0 = a2; }
  mOut = m0; aOut = a0;
}

// ---- h1 = (adj @ feats) @ conv1_w ; block=row i, 256 thr ----
__global__ void k_enc1(const float* __restrict__ adj, const float* __restrict__ feats,
                       const float* __restrict__ w1, float* __restrict__ h1) {
  int i = blockIdx.x, t = threadIdx.x;
  __shared__ float p[16][17];
  __shared__ float t1[16];
  int k = t & 15, part = t >> 4;
  float s = 0.f;
  for (int j = part * 6; j < part * 6 + 6; ++j) s += adj[i * N + j] * feats[j * DIN + k];
  p[part][k] = s;
  __syncthreads();
  if (t < 16) { float q = 0.f; for (int r = 0; r < 16; ++r) q += p[r][t]; t1[t] = q; }
  __syncthreads();
  float h = 0.f;
  for (int kk = 0; kk < 16; ++kk) h += t1[kk] * w1[kk * HID + t];
  h1[i * HID + t] = h;
}

// ---- BN1 + ReLU ; block=col c, 128 thr ----
__global__ void k_bn1(const float* __restrict__ h1, const float* __restrict__ gg,
                      const float* __restrict__ bb, float* __restrict__ x1) {
  int c = blockIdx.x, t = threadIdx.x;
  float v = (t < N) ? h1[t * HID + c] : 0.f;
  __shared__ float s1[128], s2[128];
  s1[t] = v; s2[t] = v * v; __syncthreads();
  for (int s = 64; s > 0; s >>= 1) { if (t < s) { s1[t] += s1[t + s]; s2[t] += s2[t + s]; } __syncthreads(); }
  float mu = s1[0] / (float)N;
  float var = s2[0] / (float)N - mu * mu;
  float inv = rsqrtf(var + 1e-5f);
  if (t < N) x1[t * HID + c] = fmaxf((v - mu) * inv * gg[c] + bb[c], 0.f);
}

// ---- h2 = (adj @ x1) @ conv2_w ; block=row i, 256 thr ----
__global__ void k_enc2(const float* __restrict__ adj, const float* __restrict__ x1,
                       const float* __restrict__ w2, float* __restrict__ h2) {
  int i = blockIdx.x, t = threadIdx.x;
  __shared__ float t2[HID];
  float s = 0.f;
  for (int j = 0; j < N; ++j) s += adj[i * N + j] * x1[j * HID + t];
  t2[t] = s;
  __syncthreads();
  float h = 0.f;
  for (int k = 0; k < HID; ++k) h += t2[k] * w2[k * HID + t];
  h2[i * HID + t] = h;
}

// ---- BN2 then gh = column sums ; block=col c ----
__global__ void k_bn2gh(const float* __restrict__ h2, const float* __restrict__ gg,
                        const float* __restrict__ bb, float* __restrict__ gh) {
  int c = blockIdx.x, t = threadIdx.x;
  float v = (t < N) ? h2[t * HID + c] : 0.f;
  __shared__ float s1[128], s2[128];
  s1[t] = v; s2[t] = v * v; __syncthreads();
  for (int s = 64; s > 0; s >>= 1) { if (t < s) { s1[t] += s1[t + s]; s2[t] += s2[t + s]; } __syncthreads(); }
  float mu = s1[0] / (float)N;
  float var = s2[0] / (float)N - mu * mu;
  float inv = rsqrtf(var + 1e-5f);
  __syncthreads();
  float xv = (t < N) ? ((v - mu) * inv * gg[c] + bb[c]) : 0.f;
  s1[t] = xv; __syncthreads();
  for (int s = 64; s > 0; s >>= 1) { if (t < s) s1[t] += s1[t + s]; __syncthreads(); }
  if (t == 0) gh[c] = s1[0];
}

// ---- VAE (redundant per block) + decoder ; 25 blocks x 256 thr ----
__global__ void k_vaedec(const float* __restrict__ gh,
                         const float* __restrict__ e11w, const float* __restrict__ e11b,
                         const float* __restrict__ e12w, const float* __restrict__ e12b,
                         const float* __restrict__ d1w, const float* __restrict__ d1b,
                         const float* __restrict__ d2w, const float* __restrict__ d2b,
                         const float* __restrict__ eps, float* __restrict__ kl,
                         float* __restrict__ outp, float* __restrict__ outx) {
  int t = threadIdx.x;
  __shared__ float ghs[HID], zs[LAT], h1d[LAT], kr[LAT];
  ghs[t] = gh[t];
  __syncthreads();
  if (t < LAT) {
    float a = e11b[t], c = e12b[t];
    for (int k = 0; k < HID; ++k) {
      float g = ghs[k];
      a = fmaf(e11w[t * HID + k], g, a);
      c = fmaf(e12w[t * HID + k], g, c);
    }
    zs[t] = eps[t] * expf(0.5f * c) + a;
    kr[t] = 1.f + c - a * a - expf(c);
  }
  __syncthreads();
  if (blockIdx.x == 0 && t == 0) {
    float s = 0.f;
    for (int k = 0; k < LAT; ++k) s += kr[k];
    kl[0] = -0.5f * s / (float)(N * N);
  }
  if (t < LAT) {
    float hv = d1b[t];
    for (int k = 0; k < LAT; ++k) hv = fmaf(d1w[t * LAT + k], zs[k], hv);
    h1d[t] = fmaxf(hv, 0.f);
  }
  __syncthreads();
  int o = blockIdx.x * 256 + t;
  if (o < OUTDIM) {
    const float4* wr = (const float4*)(d2w + o * LAT);
    float s = d2b[o];
    for (int k4 = 0; k4 < 32; ++k4) {
      float4 v = wr[k4];
      s = fmaf(v.x, h1d[k4 * 4], fmaf(v.y, h1d[k4 * 4 + 1],
            fmaf(v.z, h1d[k4 * 4 + 2], fmaf(v.w, h1d[k4 * 4 + 3], s))));
    }
    if (o < EDGE) outp[o] = 1.f / (1.f + expf(-s));
    else outx[o - EDGE] = s;
  }
}

// ---- degrees, diagonals, bitmasks, x0 init ; block=row a, 128 thr ----
__global__ void k_prep(const float* __restrict__ adj, const float* __restrict__ outp,
                       float* __restrict__ degt, float* __restrict__ degr,
                       float* __restrict__ dt, float* __restrict__ dr,
                       ull* __restrict__ mskg, float* __restrict__ x0,
                       float* __restrict__ x0T) {
  int a = blockIdx.x, t = threadIdx.x;
  float rv = 0.f, av = 0.f;
  if (t < N) {
    int i2 = min(a, t), j2 = max(a, t);
    rv = outp[triidx(i2, j2)];
    av = adj[a * N + t];
    if (t == a) { dr[a] = rv; dt[a] = av; }
  }
  ull bal = __ballot(t < N && av > 0.5f);
  if ((t & 63) == 0) mskg[a * 2 + (t >> 6)] = bal;
  // x0 init: block a owns row a of both layouts
  if (t < 104) x0[a * 104 + t] = 1.f / (float)N;
  if (t < N) x0T[a * N + t] = 1.f / (float)N;
  __shared__ float s1[128], s2[128];
  s1[t] = rv; s2[t] = av; __syncthreads();
  for (int s = 64; s > 0; s >>= 1) { if (t < s) { s1[t] += s1[t + s]; s2[t] += s2[t + s]; } __syncthreads(); }
  if (t == 0) { degr[a] = s1[0]; degt[a] = s2[0]; }
}

// ---- one MPM iteration ; block = column a, 256 thr (2 threads per row) ----
__global__ __launch_bounds__(256) void k_mpm(
    const float* __restrict__ xin,  const float* __restrict__ xinT,
    float* __restrict__ xout, float* __restrict__ xoutT,
    const float* __restrict__ outp,
    const float* __restrict__ degt, const float* __restrict__ degr,
    const float* __restrict__ dt, const float* __restrict__ dr,
    const ull* __restrict__ mskg,
    const float* __restrict__ sspP, float* __restrict__ sspC, int first) {
  const int a = blockIdx.x, t = threadIdx.x;
  const int w = t >> 6, l = t & 63;
  const int j = t >> 1, h = t & 1;          // row j, half h (b in [48h,48h+48))
  __shared__ __align__(16) float Bs[96];
  __shared__ float Ms[96];
  __shared__ float red[4], red2[4];
  const bool act = (j < N);
  const float drA = dr[a];
  const float dgrA = degr[a];
  if (t < N) {
    int i2 = min(a, t), j2 = max(a, t);
    float rv = outp[triidx(i2, j2)];
    Bs[t] = (t == a) ? 0.f : rv * drA * dr[t];
  }
  float sv = (!first && t < N) ? sspP[t] : 0.f;
#pragma unroll
  for (int off = 32; off >= 1; off >>= 1) sv += __shfl_xor(sv, off);
  if (l == 0) red[w] = sv;
  ull wm = 0;
  if (act) {
    wm = mskg[j * 2 + h];
    if (h == 0) { if (j < 64) wm &= ~(1ull << j); }
    else        { if (j >= 64) wm &= ~(1ull << (j - 64)); }
  }
  __syncthreads();
  const float inv = first ? 1.f : rsqrtf(red[0] + red[1] + red[2] + red[3]);
  if (act) {
    const float4* xr = (const float4*)(xin + j * 104) + h * 12;
    const float4* Bs4 = (const float4*)Bs + h * 12;
    float m0 = 0.f;
#pragma unroll
    for (int k = 0; k < 12; ++k) {
      float4 xq = xr[k];
      float4 bq = Bs4[k];
      m0 = fmaxf(m0, fmaxf(fmaxf(bq.x * xq.x, bq.y * xq.y),
                           fmaxf(bq.z * xq.z, bq.w * xq.w)));
    }
    m0 = fmaxf(m0, __shfl_xor(m0, 1));
    if (h == 0) Ms[j] = m0;
  }
  __syncthreads();
  float ss = 0.f;
  if (act) {
    float macc = 0.f;
    ull mm = wm;
    int base = h * 64;
    while (mm) { int jj = __builtin_ctzll(mm); mm &= mm - 1; macc += Ms[base + jj]; }
    macc += __shfl_xor(macc, 1);
    if (h == 0) {
      float sd = dt[j] * drA / (fabsf(degt[j] - dgrA) + 1.f);
      float v = fmaf(xinT[a * N + j], sd, macc) * inv;
      xout[j * 104 + a] = v;
      xoutT[a * N + j] = v;
      ss = v * v;
    }
  }
#pragma unroll
  for (int off = 32; off >= 1; off >>= 1) ss += __shfl_xor(ss, off);
  if (l == 0) red2[w] = ss;
  __syncthreads();
  if (t == 0) sspC[a] = red2[0] + red2[1] + red2[2] + red2[3];
}

// ---- greedy (row-per-thread, DPP value max + ballot argmin, 1 barrier/step) ----
__global__ __launch_bounds__(128) void k_fin(
    const float* __restrict__ xfin,      // [96][104] row-major
    const ull* __restrict__ mskg,
    const float* __restrict__ feats,
    const float* __restrict__ outp, const float* __restrict__ outx,
    const float* __restrict__ kl, float* __restrict__ out) {
  int t = threadIdx.x;
  int w = t >> 6, l = t & 63;
  __shared__ float X[96 * 100];
  __shared__ int INDS[96];
  __shared__ ull MSKl[192];
  __shared__ float kwM[2][2];
  __shared__ int kwI[2][2];
  __shared__ float rf[2], rb[2];

  // fused: load own row from global -> LDS, computing initial (max, argmax)
  bool alive = (t < N);
  float mT = -FLT_MAX; int aT = 0;
  if (alive) {
    const float4* src = (const float4*)&xfin[t * 104];
    float4* dst = (float4*)&X[t * 100];
    float m0 = -FLT_MAX, m1 = -FLT_MAX, m2 = -FLT_MAX, m3 = -FLT_MAX;
    int a0 = 0, a1 = 1, a2 = 2, a3 = 3;
#pragma unroll
    for (int q = 0; q < 24; ++q) {
      float4 v = src[q];
      dst[q] = v;
      if (v.x > m0) { m0 = v.x; a0 = 4 * q; }
      if (v.y > m1) { m1 = v.y; a1 = 4 * q + 1; }
      if (v.z > m2) { m2 = v.z; a2 = 4 * q + 2; }
      if (v.w > m3) { m3 = v.w; a3 = 4 * q + 3; }
    }
    if (m1 > m0 || (m1 == m0 && a1 < a0)) { m0 = m1; a0 = a1; }
    if (m3 > m2 || (m3 == m2 && a3 < a2)) { m2 = m3; a2 = a3; }
    if (m2 > m0 || (m2 == m0 && a2 < a0)) { m0 = m2; a0 = a2; }
    mT = m0; aT = a0;
  }
  if (t < 96) { MSKl[2 * t] = mskg[2 * t]; MSKl[2 * t + 1] = mskg[2 * t + 1]; }
  __syncthreads();

  for (int step = 0; step < N; ++step) {
    // per-wave value max (pure VALU DPP)
    float vc = alive ? mT : -FLT_MAX;
    FMAXDPP(vc, 0x111, 0xF);   // row_shr:1
    FMAXDPP(vc, 0x112, 0xF);   // row_shr:2
    FMAXDPP(vc, 0x114, 0xF);   // row_shr:4
    FMAXDPP(vc, 0x118, 0xF);   // row_shr:8
    FMAXDPP(vc, 0x142, 0xA);   // row_bcast15
    FMAXDPP(vc, 0x143, 0xC);   // row_bcast31
    float Mw = __int_as_float(__builtin_amdgcn_readlane(__float_as_int(vc), 63));
    // winner lane = lowest lane with mT==Mw (rows ascend with lane -> smallest flat)
    ull b = __ballot(alive && mT == Mw);
    int wl = (b == 0) ? 0 : (int)__builtin_ctzll(b);
    int sl = step & 1;
    if (l == wl) kwI[sl][w] = (b == 0) ? 0x7FFFFFFF : (t * N + aT);
    if (l == 0) kwM[sl][w] = Mw;
    __syncthreads();
    float M0 = kwM[sl][0], M1 = kwM[sl][1];
    int F = (M1 > M0) ? kwI[sl][1] : kwI[sl][0];   // tie -> wave0 (smaller flats)
    int r = F / N, c = F - (F / N) * N;
    if (t == r) { INDS[c] = r; alive = false; }
    if (t < N) X[t * 100 + c] = -FLT_MAX;          // own-row clear (no hazard)
    if (alive && aT == c) scan_row(&X[t * 100], mT, aT);  // parallel rescan
  }
  __syncthreads();

  // ---- losses ----
  float accf = 0.f;
  for (int p = t; p < N * DIN; p += 128) {
    int i = p >> 4, k = p & 15;
    float d = outx[p] - feats[INDS[i] * DIN + k];
    accf += d * d;
  }
  float accb = 0.f;
  for (int e = t; e < EDGE; e += 128) {
    int i = (int)((193.0f - sqrtf(193.0f * 193.0f - 8.0f * (float)e)) * 0.5f);
    if (i < 0) i = 0; if (i > 95) i = 95;
    while (i < 95 && triidx(i + 1, i + 1) <= e) ++i;
    while (i > 0 && triidx(i, i) > e) --i;
    int j = i + (e - triidx(i, i));
    int ri = INDS[i], rj = INDS[j];
    float tv = (float)((MSKl[ri * 2 + (rj >> 6)] >> (rj & 63)) & 1ull);
    float pr = outp[e];
    float l1 = fmaxf(logf(pr), -100.f);
    float l0 = fmaxf(log1pf(-pr), -100.f);
    accb += tv * l1 + (1.f - tv) * l0;
  }
#pragma unroll
  for (int off = 32; off >= 1; off >>= 1) { accf += __shfl_xor(accf, off); accb += __shfl_xor(accb, off); }
  if (l == 0) { rf[w] = accf; rb[w] = accb; }
  __syncthreads();
  if (t == 0) {
    float ff = rf[0] + rf[1];
    float bb = rb[0] + rb[1];
    out[0] = (-bb / (float)EDGE) + kl[0] + ff / (float)(N * DIN);
  }
}

extern "C" void kernel_launch(void* const* d_in, const int* in_sizes, int n_in,
                              void* d_out, int out_size, void* d_ws, size_t ws_size,
                              hipStream_t stream) {
  const float* feats = (const float*)d_in[0];
  const float* adj   = (const float*)d_in[1];
  const float* w1    = (const float*)d_in[2];
  const float* w2    = (const float*)d_in[3];
  const float* bn1g  = (const float*)d_in[4];
  const float* bn1b  = (const float*)d_in[5];
  const float* bn2g  = (const float*)d_in[6];
  const float* bn2b  = (const float*)d_in[7];
  const float* e11w  = (const float*)d_in[8];
  const float* e11b  = (const float*)d_in[9];
  const float* e12w  = (const float*)d_in[10];
  const float* e12b  = (const float*)d_in[11];
  const float* d1w   = (const float*)d_in[12];
  const float* d1b   = (const float*)d_in[13];
  const float* d2w   = (const float*)d_in[14];
  const float* d2b   = (const float*)d_in[15];
  const float* eps   = (const float*)d_in[16];

  float* ws   = (float*)d_ws;
  float* h1   = ws + WH1;
  float* x1   = ws + WX1;
  float* h2   = ws + WH2;
  float* gh   = ws + WGH;
  float* kl   = ws + WKL;
  float* outp = ws + WOUTP;
  float* outx = ws + WOUTX;
  float* degt = ws + WDEGT;
  float* degr = ws + WDEGR;
  float* dt   = ws + WDT;
  float* dr   = ws + WDR;
  ull*   mskg = (ull*)(ws + WMSK);
  float* xa   = ws + WXA;
  float* xb   = ws + WXB;
  float* xaT  = ws + WXAT;
  float* xbT  = ws + WXBT;
  float* ssp  = ws + WSSP;
  float* out  = (float*)d_out;

  k_enc1<<<96, 256, 0, stream>>>(adj, feats, w1, h1);
  k_bn1<<<256, 128, 0, stream>>>(h1, bn1g, bn1b, x1);
  k_enc2<<<96, 256, 0, stream>>>(adj, x1, w2, h2);
  k_bn2gh<<<256, 128, 0, stream>>>(h2, bn2g, bn2b, gh);
  k_vaedec<<<25, 256, 0, stream>>>(gh, e11w, e11b, e12w, e12b, d1w, d1b,
                                   d2w, d2b, eps, kl, outp, outx);
  k_prep<<<96, 128, 0, stream>>>(adj, outp, degt, degr, dt, dr, mskg, xa, xaT);

  for (int m = 0; m < 50; ++m) {
    const float* xi  = (m & 1) ? xb : xa;
    const float* xiT = (m & 1) ? xbT : xaT;
    float* xo        = (m & 1) ? xa : xb;
    float* xoT       = (m & 1) ? xaT : xbT;
    float* sc        = ssp + (m & 1) * N;
    const float* sp  = ssp + ((m & 1) ^ 1) * N;
    k_mpm<<<96, 256, 0, stream>>>(xi, xiT, xo, xoT, outp, degt, degr, dt, dr,
                                  mskg, sp, sc, (m == 0) ? 1 : 0);
  }
  // m=49 odd -> final x in xa
  k_fin<<<1, 128, 0, stream>>>(xa, mskg, feats, outp, outx, kl, out);
}